// Round 1
// baseline (687.647 us; speedup 1.0000x reference)
//
#include <hip/hip_runtime.h>
#include <hip/hip_bf16.h>

// Problem constants
#define NB 64
#define NT 256
#define TC 16
#define NL 25
#define NWORDS 16384   // NB*NT
#define DWd 150        // word-LSTM input dim
#define WEd 100

__device__ __forceinline__ float sigf(float x){ return __fdividef(1.f, 1.f + __expf(-x)); }
__device__ __forceinline__ float tanhf_(float x){
    float ax = fabsf(x);
    float e = __expf(-2.f*ax);                 // e in (0,1], overflow-safe
    float r = (1.f - e) * __fdividef(1.f, 1.f + e);
    return copysignf(r, x);
}

// ---------------- Kernel 0: gxc[c][dir][u][q] = cb[q*25+u] + sum_k char_emb[c][k]*cWih[k][q*25+u]
__global__ void k_gxc(const float* __restrict__ char_emb,
                      const float* __restrict__ cWih_f, const float* __restrict__ cb_f,
                      const float* __restrict__ cWih_b, const float* __restrict__ cb_b,
                      float* __restrict__ gxc){
  int i = blockIdx.x*blockDim.x + threadIdx.x;
  if (i >= 128*2*25*4) return;
  int q = i & 3; int t = i >> 2; int u = t % 25; int t2 = t / 25; int d = t2 & 1; int c = t2 >> 1;
  const float* Wih = d ? cWih_b : cWih_f;
  const float* bb  = d ? cb_b  : cb_f;
  int col = q*25 + u;
  float acc = bb[col];
  #pragma unroll
  for (int k=0;k<25;k++) acc += char_emb[c*25+k]*Wih[k*100+col];
  gxc[i] = acc;
}

// ---------------- Kernel 1: char BiLSTM last hidden -> cf[word][50]
// thread = (word, dir, half): 65536 threads; state in LDS; Whh packed in LDS.
__global__ __launch_bounds__(256) void k_char(const int* __restrict__ char_tensor,
   const int* __restrict__ char_lengths,
   const float* __restrict__ cWhh_f, const float* __restrict__ cWhh_b,
   const float* __restrict__ gxc, float* __restrict__ cf){
  __shared__ float wh4[2][25][26][4];   // [dir][k][u(pad 26)][gate]
  __shared__ float hs[2][64][2][26];    // [buf][word_local][dir][u(pad)]
  __shared__ float cs[64][2][26];
  int tid = threadIdx.x;
  for (int i=tid; i<5000; i+=256){
    int d = i/2500; int r = i%2500; int k = r/100; int cq = r%100; int u = cq>>2; int q = cq&3;
    const float* W = d ? cWhh_b : cWhh_f;
    wh4[d][k][u][q] = W[k*100 + q*25 + u];
  }
  for (int i=tid; i<200; i+=256){       // zero pad row u=25
    int d = i/100; int r = i%100; int k = r>>2; int q = r&3;
    wh4[d][k][25][q] = 0.f;
  }
  int gtid = blockIdx.x*256 + tid;
  int w = gtid>>2; int sub = gtid&3; int dir = sub>>1; int half = sub&1;
  int u0 = half*13;
  int lw = tid>>2;
  #pragma unroll
  for (int ub=0; ub<13; ub++){ hs[0][lw][dir][u0+ub]=0.f; cs[lw][dir][u0+ub]=0.f; }
  __syncthreads();
  int len = char_lengths[w];
  const int* crow = char_tensor + w*TC;
  for (int t=0;t<TC;t++){
    if (t<len){
      int cidx = crow[dir ? (len-1-t) : t];
      const float4* gx4 = (const float4*)(gxc + (size_t)((cidx*2+dir)*25)*4);
      float4 acc[13];
      #pragma unroll
      for (int ub=0; ub<13; ub++) acc[ub] = gx4[u0+ub];
      int cur = t&1;
      #pragma unroll
      for (int k=0;k<25;k++){
        float hk = hs[cur][lw][dir][k];
        #pragma unroll
        for (int ub=0;ub<13;ub++){
          float4 wv = *(const float4*)&wh4[dir][k][u0+ub][0];
          acc[ub].x += hk*wv.x; acc[ub].y += hk*wv.y;
          acc[ub].z += hk*wv.z; acc[ub].w += hk*wv.w;
        }
      }
      int nxt = cur^1;
      #pragma unroll
      for (int ub=0;ub<13;ub++){
        int u = u0+ub;
        float cc = cs[lw][dir][u];
        float cn = sigf(acc[ub].y)*cc + sigf(acc[ub].x)*tanhf_(acc[ub].z);
        cs[lw][dir][u] = cn;
        hs[nxt][lw][dir][u] = sigf(acc[ub].w)*tanhf_(cn);
      }
    }
    __syncthreads();
  }
  int fb = len&1;
  #pragma unroll
  for (int ub=0;ub<13;ub++){
    int u = u0+ub;
    if (u<25) cf[w*50 + dir*25 + u] = hs[fb][lw][dir][u];
  }
}

// ---------------- Kernel 2: x[p][150] = word_emb[tok[p]] ++ cf[recover[p]]
__global__ void k_buildx(const int* __restrict__ tok, const int* __restrict__ recover,
                         const float* __restrict__ word_emb, const float* __restrict__ cf,
                         float* __restrict__ x){
  long i = (long)blockIdx.x*blockDim.x + threadIdx.x;
  if (i >= (long)NWORDS*DWd) return;
  int p = (int)(i/DWd); int e = (int)(i - (long)p*DWd);
  float v;
  if (e < WEd) v = word_emb[(long)tok[p]*WEd + e];
  else         v = cf[recover[p]*50 + (e-WEd)];
  x[i] = v;
}

// ---------------- Kernel 3: gx[d][p][400] = wb_d + x[p] @ wWih_d   (fp32 tiled GEMM, M=16384,N=800,K=150)
__global__ __launch_bounds__(256) void k_wih(const float* __restrict__ x,
    const float* __restrict__ Wf, const float* __restrict__ bf,
    const float* __restrict__ Wb, const float* __restrict__ bbias,
    float* __restrict__ gx){
  __shared__ float As[150][36];  // transposed A tile, pad 36 keeps 16B alignment
  int tid = threadIdx.x;
  int m0 = (blockIdx.x>>2)*32;
  int nt = blockIdx.x & 3;
  int n0 = nt*256;
  for (int i=tid; i<32*150; i+=256){
    int r = i/150; int k = i - r*150;
    As[k][r] = x[(long)(m0+r)*150 + k];
  }
  __syncthreads();
  int tn = tid & 31; int tm = tid >> 5;
  int j0 = n0 + tn*8;
  bool colok = j0 < 800;
  int d = (j0 >= 400) ? 1 : 0;
  const float* W = d ? Wb : Wf;
  int jc = j0 - d*400;
  float acc[4][8];
  #pragma unroll
  for (int mi=0;mi<4;mi++)
    #pragma unroll
    for (int ni=0;ni<8;ni++) acc[mi][ni]=0.f;
  if (colok){
    for (int k=0;k<150;k++){
      float4 b0 = *(const float4*)&W[k*400 + jc];
      float4 b1 = *(const float4*)&W[k*400 + jc + 4];
      float4 a4 = *(const float4*)&As[k][tm*4];
      float av[4] = {a4.x,a4.y,a4.z,a4.w};
      float bv[8] = {b0.x,b0.y,b0.z,b0.w,b1.x,b1.y,b1.z,b1.w};
      #pragma unroll
      for (int mi=0;mi<4;mi++)
        #pragma unroll
        for (int ni=0;ni<8;ni++) acc[mi][ni] += av[mi]*bv[ni];
    }
    const float* bptr = d ? bbias : bf;
    float bias[8];
    #pragma unroll
    for (int ni=0;ni<8;ni++) bias[ni] = bptr[jc+ni];
    #pragma unroll
    for (int mi=0;mi<4;mi++){
      int p = m0 + tm*4 + mi;
      float* orow = gx + ((long)d*NWORDS + p)*400 + jc;
      #pragma unroll
      for (int ni=0;ni<8;ni++) orow[ni] = acc[mi][ni] + bias[ni];
    }
  }
}

// ---------------- Kernel 4: word LSTM recurrence. block = (seq, dir), Whh weight-stationary in VGPRs.
__global__ __launch_bounds__(448) void k_wlstm(const float* __restrict__ gx,
     const float* __restrict__ Whf, const float* __restrict__ Whb,
     float* __restrict__ hseq){
  __shared__ float h_lds[2][100];
  __shared__ float g_lds[400];
  int tid = threadIdx.x;
  int s = blockIdx.x & 63; int d = blockIdx.x >> 6;
  const float* Wh = d ? Whb : Whf;
  float wcol[100];
  if (tid<400){
    #pragma unroll
    for (int k=0;k<100;k++) wcol[k] = Wh[k*400 + tid];
  }
  if (tid<100) h_lds[0][tid] = 0.f;
  float c_reg = 0.f;
  const float* gxd = gx + (long)d*NWORDS*400 + (long)s*256*400;
  __syncthreads();
  float gnext = 0.f;
  if (tid<400) gnext = gxd[(d?255:0)*400 + tid];
  for (int t=0;t<256;t++){
    int cur = t&1, nxt = cur^1;
    float gcur = gnext;
    if (tid<400 && t+1<256){
      int ttn = d ? (255-(t+1)) : (t+1);
      gnext = gxd[ttn*400 + tid];
    }
    if (tid<400){
      float a0 = gcur, a1 = 0.f;
      const float4* h4 = (const float4*)h_lds[cur];
      #pragma unroll
      for (int k=0;k<25;k++){
        float4 hv = h4[k];
        a0 += hv.x*wcol[4*k]   + hv.z*wcol[4*k+2];
        a1 += hv.y*wcol[4*k+1] + hv.w*wcol[4*k+3];
      }
      g_lds[tid] = a0+a1;
    }
    __syncthreads();
    if (tid<100){
      float gi = g_lds[tid], gf = g_lds[100+tid], gg = g_lds[200+tid], go = g_lds[300+tid];
      c_reg = sigf(gf)*c_reg + sigf(gi)*tanhf_(gg);
      float hv = sigf(go)*tanhf_(c_reg);
      h_lds[nxt][tid] = hv;
      int ttc = d ? (255-t) : t;
      hseq[((long)d*NWORDS + s*256 + ttc)*100 + tid] = hv;
    }
    __syncthreads();
  }
}

// ---------------- Kernel 5: emissions em[p][25] = b_tag + concat(h_f,h_b)[p] @ W_tag
__global__ __launch_bounds__(256) void k_em(const float* __restrict__ hseq,
    const float* __restrict__ Wtag, const float* __restrict__ btag,
    float* __restrict__ em){
  __shared__ float hrow[8][200];
  __shared__ float Ws[5000];
  int tid = threadIdx.x;
  for (int i=tid;i<5000;i+=256) Ws[i] = Wtag[i];
  int p0 = blockIdx.x*8;
  for (int i=tid;i<8*200;i+=256){
    int r = i/200; int k = i - r*200;
    int p = p0+r;
    hrow[r][k] = (k<100) ? hseq[(long)p*100+k] : hseq[((long)NWORDS + p)*100 + (k-100)];
  }
  __syncthreads();
  int r = tid>>5; int c = tid&31;
  if (c<25){
    float acc = btag[c];
    for (int k=0;k<200;k++) acc += hrow[r][k]*Ws[k*25+c];
    em[(long)(p0+r)*25 + c] = acc;
  }
}

// ---------------- Kernel 6: CRF per sequence: part[s] = logZ - gold. Wave per sequence, k split across lane halves.
__global__ __launch_bounds__(64) void k_crf(const float* __restrict__ em,
    const int* __restrict__ tag, const float* __restrict__ trans,
    const float* __restrict__ start, const float* __restrict__ endv,
    float* __restrict__ part){
  int s = blockIdx.x;
  int lane = threadIdx.x;
  int j = lane & 31; int kg = lane >> 5;
  int k0 = kg ? 13 : 0; int kcnt = kg ? 12 : 13;
  const float* emb = em + (long)s*256*25;
  float tr[13];
  #pragma unroll
  for (int kk=0;kk<13;kk++){
    int k = k0+kk;
    tr[kk] = (k<25 && j<25) ? trans[k*25+j] : 0.f;
  }
  float alpha = (j<25) ? (start[j] + emb[j]) : -1e30f;
  float enext = (j<25) ? emb[25 + j] : 0.f;
  for (int t=1;t<256;t++){
    float ecur = enext;
    if (t<255 && j<25) enext = emb[(t+1)*25 + j];
    float m = -1e30f;
    #pragma unroll
    for (int kk=0;kk<13;kk++){
      if (kk<kcnt){
        float a = __shfl(alpha, k0+kk, 64);
        m = fmaxf(m, a + tr[kk]);
      }
    }
    m = fmaxf(m, __shfl_xor(m, 32, 64));
    float ssum = 0.f;
    #pragma unroll
    for (int kk=0;kk<13;kk++){
      if (kk<kcnt){
        float a = __shfl(alpha, k0+kk, 64);
        ssum += __expf(a + tr[kk] - m);
      }
    }
    ssum += __shfl_xor(ssum, 32, 64);
    float anew = __logf(ssum) + m + ecur;
    alpha = (j<25) ? anew : -1e30f;
  }
  float val = (j<25 && kg==0) ? (alpha + endv[j]) : -1e30f;
  float m2 = -1e30f;
  for (int k=0;k<25;k++) m2 = fmaxf(m2, __shfl(val, k, 64));
  float s2 = 0.f;
  for (int k=0;k<25;k++) s2 += __expf(__shfl(val, k, 64) - m2);
  float logZ = __logf(s2) + m2;
  // gold path score
  const int* tg = tag + s*256;
  float gp = 0.f;
  for (int t=lane; t<256; t+=64){
    int a = tg[t];
    gp += emb[t*25 + a];
    if (t<255) gp += trans[a*25 + tg[t+1]];
  }
  #pragma unroll
  for (int off=32; off; off>>=1) gp += __shfl_xor(gp, off, 64);
  if (lane==0){
    float gold = gp + start[tg[0]] + endv[tg[255]];
    part[s] = logZ - gold;
  }
}

// ---------------- Kernel 7: final reduce
__global__ __launch_bounds__(64) void k_red(const float* __restrict__ part, float* __restrict__ out){
  float v = part[threadIdx.x];
  #pragma unroll
  for (int off=32; off; off>>=1) v += __shfl_xor(v, off, 64);
  if (threadIdx.x==0) out[0] = v;
}

extern "C" void kernel_launch(void* const* d_in, const int* in_sizes, int n_in,
                              void* d_out, int out_size, void* d_ws, size_t ws_size,
                              hipStream_t stream){
  const int* tok          = (const int*)d_in[0];
  const int* tagp         = (const int*)d_in[1];
  const int* char_tensor  = (const int*)d_in[3];
  const int* char_lengths = (const int*)d_in[4];
  const int* recover      = (const int*)d_in[5];
  const float* word_emb = (const float*)d_in[6];
  const float* char_emb = (const float*)d_in[7];
  const float* cWih_f=(const float*)d_in[8];  const float* cWhh_f=(const float*)d_in[9];  const float* cb_f=(const float*)d_in[10];
  const float* cWih_b=(const float*)d_in[11]; const float* cWhh_b=(const float*)d_in[12]; const float* cb_b=(const float*)d_in[13];
  const float* wWih_f=(const float*)d_in[14]; const float* wWhh_f=(const float*)d_in[15]; const float* wb_f=(const float*)d_in[16];
  const float* wWih_b=(const float*)d_in[17]; const float* wWhh_b=(const float*)d_in[18]; const float* wb_b=(const float*)d_in[19];
  const float* W_tag=(const float*)d_in[20];  const float* b_tag=(const float*)d_in[21];
  const float* trans=(const float*)d_in[22];  const float* startv=(const float*)d_in[23]; const float* endv=(const float*)d_in[24];

  float* ws  = (float*)d_ws;
  float* gxc = ws;               // 25600
  float* cf  = ws + 25600;       // 819200
  float* x   = ws + 844800;      // 2457600
  float* gx  = ws + 3302400;     // 13107200
  float* hseq= ws + 16409600;    // 3276800
  float* em  = ws + 19686400;    // 409600
  float* part= ws + 20096000;    // 64
  float* out = (float*)d_out;

  k_gxc   <<<100, 256, 0, stream>>>(char_emb, cWih_f, cb_f, cWih_b, cb_b, gxc);
  k_char  <<<256, 256, 0, stream>>>(char_tensor, char_lengths, cWhh_f, cWhh_b, gxc, cf);
  k_buildx<<<9600,256, 0, stream>>>(tok, recover, word_emb, cf, x);
  k_wih   <<<2048,256, 0, stream>>>(x, wWih_f, wb_f, wWih_b, wb_b, gx);
  k_wlstm <<<128, 448, 0, stream>>>(gx, wWhh_f, wWhh_b, hseq);
  k_em    <<<2048,256, 0, stream>>>(hseq, W_tag, b_tag, em);
  k_crf   <<<64,  64,  0, stream>>>(em, tagp, trans, startv, endv, part);
  k_red   <<<1,   64,  0, stream>>>(part, out);
}

// Round 2
// 661.689 us; speedup vs baseline: 1.0392x; 1.0392x over previous
//
#include <hip/hip_runtime.h>
#include <hip/hip_bf16.h>

// Problem constants
#define NB 64
#define NT 256
#define TC 16
#define NL 25
#define NWORDS 16384   // NB*NT
#define DWd 150        // word-LSTM input dim
#define WEd 100

__device__ __forceinline__ float sigf(float x){ return __fdividef(1.f, 1.f + __expf(-x)); }
__device__ __forceinline__ float tanhf_(float x){
    float ax = fabsf(x);
    float e = __expf(-2.f*ax);                 // e in (0,1], overflow-safe
    float r = (1.f - e) * __fdividef(1.f, 1.f + e);
    return copysignf(r, x);
}
__device__ __forceinline__ float rdlane(float v, int k){
    return __int_as_float(__builtin_amdgcn_readlane(__float_as_int(v), k));
}

// ---------------- Kernel 0: gxc[c][dir][u][q] = cb[q*25+u] + sum_k char_emb[c][k]*cWih[k][q*25+u]
__global__ void k_gxc(const float* __restrict__ char_emb,
                      const float* __restrict__ cWih_f, const float* __restrict__ cb_f,
                      const float* __restrict__ cWih_b, const float* __restrict__ cb_b,
                      float* __restrict__ gxc){
  int i = blockIdx.x*blockDim.x + threadIdx.x;
  if (i >= 128*2*25*4) return;
  int q = i & 3; int t = i >> 2; int u = t % 25; int t2 = t / 25; int d = t2 & 1; int c = t2 >> 1;
  const float* Wih = d ? cWih_b : cWih_f;
  const float* bb  = d ? cb_b  : cb_f;
  int col = q*25 + u;
  float acc = bb[col];
  #pragma unroll
  for (int k=0;k<25;k++) acc += char_emb[c*25+k]*Wih[k*100+col];
  gxc[i] = acc;
}

// ---------------- Kernel 1: char BiLSTM last hidden -> cf[word][50]
// thread = (word, dir, half): 65536 threads; state in LDS; Whh packed in LDS.
__global__ __launch_bounds__(256) void k_char(const int* __restrict__ char_tensor,
   const int* __restrict__ char_lengths,
   const float* __restrict__ cWhh_f, const float* __restrict__ cWhh_b,
   const float* __restrict__ gxc, float* __restrict__ cf){
  __shared__ float wh4[2][25][26][4];   // [dir][k][u(pad 26)][gate]
  __shared__ float hs[2][64][2][26];    // [buf][word_local][dir][u(pad)]
  __shared__ float cs[64][2][26];
  int tid = threadIdx.x;
  for (int i=tid; i<5000; i+=256){
    int d = i/2500; int r = i%2500; int k = r/100; int cq = r%100; int u = cq>>2; int q = cq&3;
    const float* W = d ? cWhh_b : cWhh_f;
    wh4[d][k][u][q] = W[k*100 + q*25 + u];
  }
  for (int i=tid; i<200; i+=256){       // zero pad row u=25
    int d = i/100; int r = i%100; int k = r>>2; int q = r&3;
    wh4[d][k][25][q] = 0.f;
  }
  int gtid = blockIdx.x*256 + tid;
  int w = gtid>>2; int sub = gtid&3; int dir = sub>>1; int half = sub&1;
  int u0 = half*13;
  int lw = tid>>2;
  #pragma unroll
  for (int ub=0; ub<13; ub++){ hs[0][lw][dir][u0+ub]=0.f; cs[lw][dir][u0+ub]=0.f; }
  __syncthreads();
  int len = char_lengths[w];
  const int* crow = char_tensor + w*TC;
  for (int t=0;t<TC;t++){
    if (t<len){
      int cidx = crow[dir ? (len-1-t) : t];
      const float4* gx4 = (const float4*)(gxc + (size_t)((cidx*2+dir)*25)*4);
      float4 acc[13];
      #pragma unroll
      for (int ub=0; ub<13; ub++) acc[ub] = gx4[u0+ub];
      int cur = t&1;
      #pragma unroll
      for (int k=0;k<25;k++){
        float hk = hs[cur][lw][dir][k];
        #pragma unroll
        for (int ub=0;ub<13;ub++){
          float4 wv = *(const float4*)&wh4[dir][k][u0+ub][0];
          acc[ub].x += hk*wv.x; acc[ub].y += hk*wv.y;
          acc[ub].z += hk*wv.z; acc[ub].w += hk*wv.w;
        }
      }
      int nxt = cur^1;
      #pragma unroll
      for (int ub=0;ub<13;ub++){
        int u = u0+ub;
        float cc = cs[lw][dir][u];
        float cn = sigf(acc[ub].y)*cc + sigf(acc[ub].x)*tanhf_(acc[ub].z);
        cs[lw][dir][u] = cn;
        hs[nxt][lw][dir][u] = sigf(acc[ub].w)*tanhf_(cn);
      }
    }
    __syncthreads();
  }
  int fb = len&1;
  #pragma unroll
  for (int ub=0;ub<13;ub++){
    int u = u0+ub;
    if (u<25) cf[w*50 + dir*25 + u] = hs[fb][lw][dir][u];
  }
}

// ---------------- Kernel 2: x[p][150] = word_emb[tok[p]] ++ cf[recover[p]]
__global__ void k_buildx(const int* __restrict__ tok, const int* __restrict__ recover,
                         const float* __restrict__ word_emb, const float* __restrict__ cf,
                         float* __restrict__ x){
  long i = (long)blockIdx.x*blockDim.x + threadIdx.x;
  if (i >= (long)NWORDS*DWd) return;
  int p = (int)(i/DWd); int e = (int)(i - (long)p*DWd);
  float v;
  if (e < WEd) v = word_emb[(long)tok[p]*WEd + e];
  else         v = cf[recover[p]*50 + (e-WEd)];
  x[i] = v;
}

// ---------------- Kernel 3: gx[d][p][400] = wb_d + x[p] @ wWih_d   (fp32 tiled GEMM, M=16384,N=800,K=150)
__global__ __launch_bounds__(256) void k_wih(const float* __restrict__ x,
    const float* __restrict__ Wf, const float* __restrict__ bf,
    const float* __restrict__ Wb, const float* __restrict__ bbias,
    float* __restrict__ gx){
  __shared__ float As[150][36];  // transposed A tile, pad 36 keeps 16B alignment
  int tid = threadIdx.x;
  int m0 = (blockIdx.x>>2)*32;
  int nt = blockIdx.x & 3;
  int n0 = nt*256;
  for (int i=tid; i<32*150; i+=256){
    int r = i/150; int k = i - r*150;
    As[k][r] = x[(long)(m0+r)*150 + k];
  }
  __syncthreads();
  int tn = tid & 31; int tm = tid >> 5;
  int j0 = n0 + tn*8;
  bool colok = j0 < 800;
  int d = (j0 >= 400) ? 1 : 0;
  const float* W = d ? Wb : Wf;
  int jc = j0 - d*400;
  float acc[4][8];
  #pragma unroll
  for (int mi=0;mi<4;mi++)
    #pragma unroll
    for (int ni=0;ni<8;ni++) acc[mi][ni]=0.f;
  if (colok){
    for (int k=0;k<150;k++){
      float4 b0 = *(const float4*)&W[k*400 + jc];
      float4 b1 = *(const float4*)&W[k*400 + jc + 4];
      float4 a4 = *(const float4*)&As[k][tm*4];
      float av[4] = {a4.x,a4.y,a4.z,a4.w};
      float bv[8] = {b0.x,b0.y,b0.z,b0.w,b1.x,b1.y,b1.z,b1.w};
      #pragma unroll
      for (int mi=0;mi<4;mi++)
        #pragma unroll
        for (int ni=0;ni<8;ni++) acc[mi][ni] += av[mi]*bv[ni];
    }
    const float* bptr = d ? bbias : bf;
    float bias[8];
    #pragma unroll
    for (int ni=0;ni<8;ni++) bias[ni] = bptr[jc+ni];
    #pragma unroll
    for (int mi=0;mi<4;mi++){
      int p = m0 + tm*4 + mi;
      float* orow = gx + ((long)d*NWORDS + p)*400 + jc;
      #pragma unroll
      for (int ni=0;ni<8;ni++) orow[ni] = acc[mi][ni] + bias[ni];
    }
  }
}

// ---------------- Kernel 4: word LSTM recurrence.
// block = (seq, dir), 256 threads (4 waves). Threads 0..199 own adjacent
// gate columns (2t, 2t+1): weights stationary in 200 VGPRs (launch_bounds(256,1)
// lifts the register cap -> no spill). h distributed via v_readlane instead of
// LDS broadcast: 2 ds_read_b32 per wave per step, then readlane+2xFMA per k.
__global__ __launch_bounds__(256, 1) void k_wlstm(const float* __restrict__ gx,
     const float* __restrict__ Whf, const float* __restrict__ Whb,
     float* __restrict__ hseq){
  __shared__ float h_lds[104];
  __shared__ float act[400];
  int tid = threadIdx.x;
  int lane = tid & 63;
  int s = blockIdx.x & 63; int d = blockIdx.x >> 6;
  const float* Wh = d ? Whb : Whf;
  int j0 = 2*tid;
  float wA[100], wB[100];
  if (tid < 200){
    #pragma unroll
    for (int k=0;k<100;k++){
      wA[k] = Wh[k*400 + j0];
      wB[k] = Wh[k*400 + j0 + 1];
    }
  }
  if (tid < 104) h_lds[tid] = 0.f;
  float c_reg = 0.f;
  const float* gxd = gx + ((long)d*NWORDS + (long)s*256)*400;
  int region = tid/50;   // col 2t: 0=i,1=f,2=g,3=o
  __syncthreads();
  float2 gnext = make_float2(0.f, 0.f);
  if (tid < 200){
    int t0 = d ? 255 : 0;
    gnext = *(const float2*)&gxd[t0*400 + j0];
  }
  for (int t=0;t<256;t++){
    // h from previous step (all lanes load so readlane sources are valid)
    float hreg0 = h_lds[lane];
    float hreg1 = (lane < 36) ? h_lds[64 + lane] : 0.f;
    float2 gcur = gnext;
    if (tid < 200 && t+1 < 256){
      int tn = d ? (255-(t+1)) : (t+1);
      gnext = *(const float2*)&gxd[tn*400 + j0];
    }
    if (tid < 200){
      float ax = gcur.x, ay = gcur.y;
      #pragma unroll
      for (int k=0;k<64;k++){
        float hk = rdlane(hreg0, k);
        ax += hk*wA[k];
        ay += hk*wB[k];
      }
      #pragma unroll
      for (int k=0;k<36;k++){
        float hk = rdlane(hreg1, k);
        ax += hk*wA[64+k];
        ay += hk*wB[64+k];
      }
      float2 v;
      if (region == 2){ v.x = tanhf_(ax); v.y = tanhf_(ay); }
      else            { v.x = sigf(ax);   v.y = sigf(ay);  }
      *(float2*)&act[j0] = v;
    }
    __syncthreads();   // act visible; everyone done reading h_lds
    if (tid < 100){
      float si = act[tid], sf = act[100+tid], sg = act[200+tid], so = act[300+tid];
      c_reg = sf*c_reg + si*sg;
      float hv = so*tanhf_(c_reg);
      h_lds[tid] = hv;
      int ttc = d ? (255-t) : t;
      hseq[((long)d*NWORDS + s*256 + ttc)*100 + tid] = hv;
    }
    __syncthreads();   // new h visible
  }
}

// ---------------- Kernel 5: emissions em[p][25] = b_tag + concat(h_f,h_b)[p] @ W_tag
__global__ __launch_bounds__(256) void k_em(const float* __restrict__ hseq,
    const float* __restrict__ Wtag, const float* __restrict__ btag,
    float* __restrict__ em){
  __shared__ float hrow[8][200];
  __shared__ float Ws[5000];
  int tid = threadIdx.x;
  for (int i=tid;i<5000;i+=256) Ws[i] = Wtag[i];
  int p0 = blockIdx.x*8;
  for (int i=tid;i<8*200;i+=256){
    int r = i/200; int k = i - r*200;
    int p = p0+r;
    hrow[r][k] = (k<100) ? hseq[(long)p*100+k] : hseq[((long)NWORDS + p)*100 + (k-100)];
  }
  __syncthreads();
  int r = tid>>5; int c = tid&31;
  if (c<25){
    float acc = btag[c];
    for (int k=0;k<200;k++) acc += hrow[r][k]*Ws[k*25+c];
    em[(long)(p0+r)*25 + c] = acc;
  }
}

// ---------------- Kernel 6: CRF per sequence: part[s] = logZ - gold.
__global__ __launch_bounds__(64) void k_crf(const float* __restrict__ em,
    const int* __restrict__ tag, const float* __restrict__ trans,
    const float* __restrict__ start, const float* __restrict__ endv,
    float* __restrict__ part){
  int s = blockIdx.x;
  int lane = threadIdx.x;
  int j = lane & 31; int kg = lane >> 5;
  int k0 = kg ? 13 : 0; int kcnt = kg ? 12 : 13;
  const float* emb = em + (long)s*256*25;
  float tr[13];
  #pragma unroll
  for (int kk=0;kk<13;kk++){
    int k = k0+kk;
    tr[kk] = (k<25 && j<25) ? trans[k*25+j] : 0.f;
  }
  float alpha = (j<25) ? (start[j] + emb[j]) : -1e30f;
  float enext = (j<25) ? emb[25 + j] : 0.f;
  for (int t=1;t<256;t++){
    float ecur = enext;
    if (t<255 && j<25) enext = emb[(t+1)*25 + j];
    float m = -1e30f;
    #pragma unroll
    for (int kk=0;kk<13;kk++){
      if (kk<kcnt){
        float a = __shfl(alpha, k0+kk, 64);
        m = fmaxf(m, a + tr[kk]);
      }
    }
    m = fmaxf(m, __shfl_xor(m, 32, 64));
    float ssum = 0.f;
    #pragma unroll
    for (int kk=0;kk<13;kk++){
      if (kk<kcnt){
        float a = __shfl(alpha, k0+kk, 64);
        ssum += __expf(a + tr[kk] - m);
      }
    }
    ssum += __shfl_xor(ssum, 32, 64);
    float anew = __logf(ssum) + m + ecur;
    alpha = (j<25) ? anew : -1e30f;
  }
  float val = (j<25 && kg==0) ? (alpha + endv[j]) : -1e30f;
  float m2 = -1e30f;
  for (int k=0;k<25;k++) m2 = fmaxf(m2, __shfl(val, k, 64));
  float s2 = 0.f;
  for (int k=0;k<25;k++) s2 += __expf(__shfl(val, k, 64) - m2);
  float logZ = __logf(s2) + m2;
  // gold path score
  const int* tg = tag + s*256;
  float gp = 0.f;
  for (int t=lane; t<256; t+=64){
    int a = tg[t];
    gp += emb[t*25 + a];
    if (t<255) gp += trans[a*25 + tg[t+1]];
  }
  #pragma unroll
  for (int off=32; off; off>>=1) gp += __shfl_xor(gp, off, 64);
  if (lane==0){
    float gold = gp + start[tg[0]] + endv[tg[255]];
    part[s] = logZ - gold;
  }
}

// ---------------- Kernel 7: final reduce
__global__ __launch_bounds__(64) void k_red(const float* __restrict__ part, float* __restrict__ out){
  float v = part[threadIdx.x];
  #pragma unroll
  for (int off=32; off; off>>=1) v += __shfl_xor(v, off, 64);
  if (threadIdx.x==0) out[0] = v;
}

extern "C" void kernel_launch(void* const* d_in, const int* in_sizes, int n_in,
                              void* d_out, int out_size, void* d_ws, size_t ws_size,
                              hipStream_t stream){
  const int* tok          = (const int*)d_in[0];
  const int* tagp         = (const int*)d_in[1];
  const int* char_tensor  = (const int*)d_in[3];
  const int* char_lengths = (const int*)d_in[4];
  const int* recover      = (const int*)d_in[5];
  const float* word_emb = (const float*)d_in[6];
  const float* char_emb = (const float*)d_in[7];
  const float* cWih_f=(const float*)d_in[8];  const float* cWhh_f=(const float*)d_in[9];  const float* cb_f=(const float*)d_in[10];
  const float* cWih_b=(const float*)d_in[11]; const float* cWhh_b=(const float*)d_in[12]; const float* cb_b=(const float*)d_in[13];
  const float* wWih_f=(const float*)d_in[14]; const float* wWhh_f=(const float*)d_in[15]; const float* wb_f=(const float*)d_in[16];
  const float* wWih_b=(const float*)d_in[17]; const float* wWhh_b=(const float*)d_in[18]; const float* wb_b=(const float*)d_in[19];
  const float* W_tag=(const float*)d_in[20];  const float* b_tag=(const float*)d_in[21];
  const float* trans=(const float*)d_in[22];  const float* startv=(const float*)d_in[23]; const float* endv=(const float*)d_in[24];

  float* ws  = (float*)d_ws;
  float* gxc = ws;               // 25600
  float* cf  = ws + 25600;       // 819200
  float* x   = ws + 844800;      // 2457600
  float* gx  = ws + 3302400;     // 13107200
  float* hseq= ws + 16409600;    // 3276800
  float* em  = ws + 19686400;    // 409600
  float* part= ws + 20096000;    // 64
  float* out = (float*)d_out;

  k_gxc   <<<100, 256, 0, stream>>>(char_emb, cWih_f, cb_f, cWih_b, cb_b, gxc);
  k_char  <<<256, 256, 0, stream>>>(char_tensor, char_lengths, cWhh_f, cWhh_b, gxc, cf);
  k_buildx<<<9600,256, 0, stream>>>(tok, recover, word_emb, cf, x);
  k_wih   <<<2048,256, 0, stream>>>(x, wWih_f, wb_f, wWih_b, wb_b, gx);
  k_wlstm <<<128, 256, 0, stream>>>(gx, wWhh_f, wWhh_b, hseq);
  k_em    <<<2048,256, 0, stream>>>(hseq, W_tag, b_tag, em);
  k_crf   <<<64,  64,  0, stream>>>(em, tagp, trans, startv, endv, part);
  k_red   <<<1,   64,  0, stream>>>(part, out);
}